// Round 9
// baseline (286.302 us; speedup 1.0000x reference)
//
#include <hip/hip_runtime.h>
#include <stdint.h>

typedef __attribute__((ext_vector_type(8))) short bf16x8;
typedef __attribute__((ext_vector_type(4))) float f32x4;

__device__ __forceinline__ unsigned short f2bf(float f) {
  unsigned int u = __builtin_bit_cast(unsigned int, f);
  u += 0x7fffu + ((u >> 16) & 1u);
  return (unsigned short)(u >> 16);
}
__device__ __forceinline__ float bf2f(unsigned short h) {
  unsigned int u = ((unsigned int)h) << 16;
  return __builtin_bit_cast(float, u);
}

__device__ __forceinline__ void gll16(const void* g, void* l) {
  __builtin_amdgcn_global_load_lds(
      (const __attribute__((address_space(1))) unsigned int*)g,
      (__attribute__((address_space(3))) unsigned int*)l, 16, 0, 0);
}

// Raw HW barrier intrinsic: recognized by the backend as a barrier, so NO
// implicit s_waitcnt drain is inserted (unlike asm with "memory" clobber,
// which forces vmcnt(0)+lgkmcnt(0) before it — that was rounds 7/8's bug).
#define BAR() __builtin_amdgcn_s_barrier()
// Counted vmcnt, clobber-free: 6 gll (=3 half-tiles) stay in flight.
#define VMC6() asm volatile("s_waitcnt vmcnt(6)")
// Pre-MFMA: drain this wave's LDS reads; sched_barrier pins MFMA below (r#18).
#define LGKM0()                          \
  asm volatile("s_waitcnt lgkmcnt(0)"); \
  __builtin_amdgcn_sched_barrier(0)

// ---------------------------------------------------------------------------
// 256x256 8-phase bt-GEMM (T2 swizzle + T3/T4 counted vmcnt + T5 setprio).
// C[M,N] = scale*(A[M,K].B[N,K]^T)+bias.  K%128==0, M,N%256==0.
// 512 thr = 8 waves (2 wr x 4 wc); per-wave C = 128x64 (acc[8][4] f32x4).
// LDS 128KB dynamic: A[2dbuf][2half][128][64], B same at +64KB.
// Per phase: {ds_read subtile | stage 1 half-tile | s_barrier | lgkmcnt(0) |
// MFMA quad | s_barrier}; vmcnt(6) before the barrier at ph4/ph8 only —
// the pipeline NEVER drains vmcnt to 0 in the main loop.
// Chunk swizzle: 16B chunk index ch ^= (row&7) on BOTH gll-source and ds_read.
// ---------------------------------------------------------------------------
__device__ __forceinline__ void stage2(const unsigned short* src, int ld,
                                       int rowbase, int kt, char* lds,
                                       int opofs, int dbuf, int half, int tid) {
#pragma unroll
  for (int i = 0; i < 2; i++) {
    int c = tid + i * 512;
    int r7 = c >> 3, ch = c & 7;
    int sch = ch ^ (r7 & 7);
    const char* g =
        (const char*)(src + (size_t)(rowbase + half * 128 + r7) * ld) +
        kt * 128 + sch * 16;
    gll16(g, lds + opofs + (dbuf * 2 + half) * 16384 + c * 16);
  }
}

__device__ __forceinline__ void ld_ahalf(const char* lds, int d, int mh, int wr,
                                         int lane, bf16x8 a[4][2]) {
#pragma unroll
  for (int m = 0; m < 4; m++)
#pragma unroll
    for (int kk = 0; kk < 2; kk++) {
      int r7 = wr * 64 + m * 16 + (lane & 15);
      int c = ((lane >> 4) + kk * 4) ^ (lane & 7);
      a[m][kk] =
          *(const bf16x8*)(lds + (d * 2 + mh) * 16384 + r7 * 128 + c * 16);
    }
}
__device__ __forceinline__ void ld_bhalf(const char* lds, int d, int nh, int wc,
                                         int lane, bf16x8 b[2][2]) {
#pragma unroll
  for (int n = 0; n < 2; n++)
#pragma unroll
    for (int kk = 0; kk < 2; kk++) {
      int r7 = wc * 32 + n * 16 + (lane & 15);
      int c = ((lane >> 4) + kk * 4) ^ (lane & 7);
      b[n][kk] = *(const bf16x8*)(lds + 65536 + (d * 2 + nh) * 16384 +
                                  r7 * 128 + c * 16);
    }
}

template <int MH, int NH>
__device__ __forceinline__ void mfma16(f32x4 acc[8][4], const bf16x8 a[4][2],
                                       const bf16x8 b[2][2]) {
  __builtin_amdgcn_s_setprio(1);
#pragma unroll
  for (int m = 0; m < 4; m++)
#pragma unroll
    for (int n = 0; n < 2; n++)
#pragma unroll
      for (int kk = 0; kk < 2; kk++)
        acc[MH * 4 + m][NH * 2 + n] = __builtin_amdgcn_mfma_f32_16x16x32_bf16(
            a[m][kk], b[n][kk], acc[MH * 4 + m][NH * 2 + n], 0, 0, 0);
  __builtin_amdgcn_s_setprio(0);
}

template <int BIASMODE, int F32OUT>
__global__ __launch_bounds__(512, 2) void gemm8(
    const unsigned short* __restrict__ A, const unsigned short* __restrict__ B,
    const float* __restrict__ bias1, const float* __restrict__ bias2,
    void* __restrict__ Cv, int K, int lda, int ldb, int ldc, long batchA,
    long batchB, long batchC, float scale) {
  extern __shared__ char lds[];
  const int z = blockIdx.z;
  A += (long)z * batchA;
  B += (long)z * batchB;

  // bijective XCD swizzle over the xy plane (nwg % 8 == 0 for all our grids)
  const int gx = gridDim.x;
  const int nwg = gx * gridDim.y;
  const int lin = blockIdx.y * gx + blockIdx.x;
  const int s = (lin & 7) * (nwg >> 3) + (lin >> 3);
  const int bn0 = (s % gx) * 256;
  const int bm0 = (s / gx) * 256;

  const int tid = threadIdx.x;
  const int lane = tid & 63;
  const int wid = tid >> 6;
  const int wr = wid >> 2, wc = wid & 3;

  f32x4 acc[8][4];
#pragma unroll
  for (int i = 0; i < 8; i++)
#pragma unroll
    for (int j = 0; j < 4; j++) acc[i][j] = (f32x4){0.f, 0.f, 0.f, 0.f};

  const int nkt = K >> 6;  // 64-wide K-tiles (even, since K%128==0)
  const int niter = nkt >> 1;

  // prologue: d0.{A0,B0,A1,B1}<-t0 ; d1.{A0,B0,A1}<-t1 (issue order = vmcnt)
  stage2(A, lda, bm0, 0, lds, 0, 0, 0, tid);
  stage2(B, ldb, bn0, 0, lds, 65536, 0, 0, tid);
  stage2(A, lda, bm0, 0, lds, 0, 0, 1, tid);
  stage2(B, ldb, bn0, 0, lds, 65536, 0, 1, tid);
  stage2(A, lda, bm0, 1, lds, 0, 1, 0, tid);
  stage2(B, ldb, bn0, 1, lds, 65536, 1, 0, tid);
  stage2(A, lda, bm0, 1, lds, 0, 1, 1, tid);
  VMC6();  // 14 issued -> oldest 8 (= all of d0) arrived; 3 half-tiles fly
  BAR();

  bf16x8 a[2][4][2], b[2][2][2];
  for (int it = 0; it < niter; ++it) {
    const int t1 = 2 * it + 1;
    int t2 = 2 * it + 2;
    if (t2 >= nkt) t2 = nkt - 1;  // clamped redundant stage keeps vmcnt exact
    int t3 = 2 * it + 3;
    if (t3 >= nkt) t3 = nkt - 1;

    // ph1: read d0.A0,d0.B0 ; stage d1.B1<-t1 ; mfma(0,0)
    ld_ahalf(lds, 0, 0, wr, lane, a[0]);
    ld_bhalf(lds, 0, 0, wc, lane, b[0]);
    stage2(B, ldb, bn0, t1, lds, 65536, 1, 1, tid);
    BAR();
    LGKM0();
    mfma16<0, 0>(acc, a[0], b[0]);
    BAR();
    // ph2: read d0.A1 ; stage d0.A0<-t2 ; mfma(1,0)
    ld_ahalf(lds, 0, 1, wr, lane, a[1]);
    stage2(A, lda, bm0, t2, lds, 0, 0, 0, tid);
    BAR();
    LGKM0();
    mfma16<1, 0>(acc, a[1], b[0]);
    BAR();
    // ph3: read d0.B1 ; stage d0.B0<-t2 ; mfma(0,1)
    ld_bhalf(lds, 0, 1, wc, lane, b[1]);
    stage2(B, ldb, bn0, t2, lds, 65536, 0, 0, tid);
    BAR();
    LGKM0();
    mfma16<0, 1>(acc, a[0], b[1]);
    BAR();
    // ph4: stage d0.A1<-t2 ; vmcnt(6) ; mfma(1,1)   [d1<-t1 fully arrived]
    stage2(A, lda, bm0, t2, lds, 0, 0, 1, tid);
    VMC6();
    BAR();
    mfma16<1, 1>(acc, a[1], b[1]);
    BAR();
    // ph5: read d1.A0,d1.B0 ; stage d0.B1<-t2 ; mfma(0,0)
    ld_ahalf(lds, 1, 0, wr, lane, a[0]);
    ld_bhalf(lds, 1, 0, wc, lane, b[0]);
    stage2(B, ldb, bn0, t2, lds, 65536, 0, 1, tid);
    BAR();
    LGKM0();
    mfma16<0, 0>(acc, a[0], b[0]);
    BAR();
    // ph6: read d1.A1 ; stage d1.A0<-t3 ; mfma(1,0)
    ld_ahalf(lds, 1, 1, wr, lane, a[1]);
    stage2(A, lda, bm0, t3, lds, 0, 1, 0, tid);
    BAR();
    LGKM0();
    mfma16<1, 0>(acc, a[1], b[0]);
    BAR();
    // ph7: read d1.B1 ; stage d1.B0<-t3 ; mfma(0,1)
    ld_bhalf(lds, 1, 1, wc, lane, b[1]);
    stage2(B, ldb, bn0, t3, lds, 65536, 1, 0, tid);
    BAR();
    LGKM0();
    mfma16<0, 1>(acc, a[0], b[1]);
    BAR();
    // ph8: stage d1.A1<-t3 ; vmcnt(6) ; mfma(1,1)   [d0<-t2 fully arrived]
    stage2(A, lda, bm0, t3, lds, 0, 1, 1, tid);
    VMC6();
    BAR();
    mfma16<1, 1>(acc, a[1], b[1]);
    BAR();
  }

  // epilogue: C/D frag layout col=lane&15, row=(lane>>4)*4+j [m89]
  const int r4 = (lane >> 4) << 2;
  const int c0 = lane & 15;
  float* Cf = (float*)Cv + (F32OUT ? (long)z * batchC : 0);
  unsigned short* Cb = (unsigned short*)Cv + (F32OUT ? 0 : (long)z * batchC);
#pragma unroll
  for (int am = 0; am < 8; am++) {
    int row = bm0 + (am >> 2) * 128 + wr * 64 + (am & 3) * 16 + r4;
#pragma unroll
    for (int an = 0; an < 4; an++) {
      int col = bn0 + (an >> 1) * 128 + wc * 32 + (an & 1) * 16 + c0;
      float bc = 0.f;
      if (BIASMODE == 1) bc = (col < 1024) ? bias1[col] : bias2[col - 1024];
      f32x4 v = acc[am][an];
#pragma unroll
      for (int j = 0; j < 4; j++) {
        float bj = (BIASMODE == 2) ? bias1[row + j] : bc;
        float r = v[j] * scale + bj;
        if (F32OUT)
          Cf[(size_t)(row + j) * ldc + col] = r;
        else
          Cb[(size_t)(row + j) * ldc + col] = f2bf(r);
      }
    }
  }
}

// ---------------------------------------------------------------------------
__global__ __launch_bounds__(256) void cvt_kernel(const float* __restrict__ in,
                                                  unsigned short* __restrict__ out,
                                                  long n4) {
  long i = (long)blockIdx.x * blockDim.x + threadIdx.x;
  long stride = (long)gridDim.x * blockDim.x;
  for (; i < n4; i += stride) {
    float4 f = ((const float4*)in)[i];
    uint2 w;
    w.x = (unsigned int)f2bf(f.x) | ((unsigned int)f2bf(f.y) << 16);
    w.y = (unsigned int)f2bf(f.z) | ((unsigned int)f2bf(f.w) << 16);
    ((uint2*)out)[i] = w;
  }
}

// ---------------------------------------------------------------------------
__global__ __launch_bounds__(1024) void transposeW_kernel(
    const float* __restrict__ W, unsigned short* __restrict__ Wt) {
  __shared__ float t[32][33];
  int x = threadIdx.x, y = threadIdx.y;
  int d = blockIdx.y * 32 + y, n = blockIdx.x * 32 + x;
  t[y][x] = W[(size_t)d * 1024 + n];
  __syncthreads();
  int nn = blockIdx.x * 32 + y, dd = blockIdx.y * 32 + x;
  Wt[(size_t)nn * 1024 + dd] = f2bf(t[x][y]);
}

// ---------------------------------------------------------------------------
__global__ __launch_bounds__(256) void softmax_kernel(unsigned short* __restrict__ SP) {
  const int row = blockIdx.x;
  unsigned short* rp = SP + (size_t)row * 2048;
  const int tid = threadIdx.x;
  const int wid = tid >> 6, lane = tid & 63;

  uint4 u = ((const uint4*)rp)[tid];  // 8 bf16
  float xv[8];
  xv[0] = bf2f(u.x & 0xffff); xv[1] = bf2f(u.x >> 16);
  xv[2] = bf2f(u.y & 0xffff); xv[3] = bf2f(u.y >> 16);
  xv[4] = bf2f(u.z & 0xffff); xv[5] = bf2f(u.z >> 16);
  xv[6] = bf2f(u.w & 0xffff); xv[7] = bf2f(u.w >> 16);

  float m = xv[0];
#pragma unroll
  for (int j = 1; j < 8; j++) m = fmaxf(m, xv[j]);
#pragma unroll
  for (int off = 32; off >= 1; off >>= 1) m = fmaxf(m, __shfl_xor(m, off));

  __shared__ float redm[4];
  __shared__ float reds[4];
  if (lane == 0) redm[wid] = m;
  __syncthreads();
  m = fmaxf(fmaxf(redm[0], redm[1]), fmaxf(redm[2], redm[3]));

  float p[8], sm = 0.f;
#pragma unroll
  for (int j = 0; j < 8; j++) {
    p[j] = __expf(xv[j] - m);
    sm += p[j];
  }
#pragma unroll
  for (int off = 32; off >= 1; off >>= 1) sm += __shfl_xor(sm, off);
  if (lane == 0) reds[wid] = sm;
  __syncthreads();
  float inv = 1.0f / (reds[0] + reds[1] + reds[2] + reds[3]);

  uint4 o;
  o.x = (unsigned int)f2bf(p[0] * inv) | ((unsigned int)f2bf(p[1] * inv) << 16);
  o.y = (unsigned int)f2bf(p[2] * inv) | ((unsigned int)f2bf(p[3] * inv) << 16);
  o.z = (unsigned int)f2bf(p[4] * inv) | ((unsigned int)f2bf(p[5] * inv) << 16);
  o.w = (unsigned int)f2bf(p[6] * inv) | ((unsigned int)f2bf(p[7] * inv) << 16);
  ((uint4*)rp)[tid] = o;
}

// ---------------------------------------------------------------------------
extern "C" void kernel_launch(void* const* d_in, const int* in_sizes, int n_in,
                              void* d_out, int out_size, void* d_ws, size_t ws_size,
                              hipStream_t stream) {
  const float* x = (const float*)d_in[0];
  const float* Wq = (const float*)d_in[1];
  const float* bq = (const float*)d_in[2];
  const float* Wk = (const float*)d_in[3];
  const float* bk = (const float*)d_in[4];
  const float* Wv = (const float*)d_in[5];
  const float* bv = (const float*)d_in[6];
  float* out = (float*)d_out;  // fp32 (reference output dtype)

  // ws layout (102 MB, round-1-exercised):
  //   [  0, 16) xb  : x bf16 [4][2048][1024]
  //   [ 16, 48) QKb : [8192][2048] bf16; cols 0-1023 = Q, 1024-2047 = K
  //   [ 48, 64) Vt  : V^T bf16 [1024 e][8192 s] (per-batch cols 2048b..+2047)
  //   [ 64, 96) SP  : scores [4][2048][2048] bf16
  //   [ 96,102) Wt  : Wtq|Wtk|Wtv bf16 transposed (contiguous: QK B-operand)
  char* ws = (char*)d_ws;
  unsigned short* xb = (unsigned short*)ws;
  unsigned short* QKb = (unsigned short*)(ws + (16L << 20));
  unsigned short* Vt = (unsigned short*)(ws + (48L << 20));
  unsigned short* SP = (unsigned short*)(ws + (64L << 20));
  unsigned short* Wtq = (unsigned short*)(ws + (96L << 20));
  unsigned short* Wtk = Wtq + 1024 * 1024;
  unsigned short* Wtv = Wtk + 1024 * 1024;

  const int LDS8 = 131072;
  (void)hipFuncSetAttribute(reinterpret_cast<const void*>(&gemm8<1, 0>),
                            hipFuncAttributeMaxDynamicSharedMemorySize, LDS8);
  (void)hipFuncSetAttribute(reinterpret_cast<const void*>(&gemm8<2, 0>),
                            hipFuncAttributeMaxDynamicSharedMemorySize, LDS8);
  (void)hipFuncSetAttribute(reinterpret_cast<const void*>(&gemm8<0, 0>),
                            hipFuncAttributeMaxDynamicSharedMemorySize, LDS8);
  (void)hipFuncSetAttribute(reinterpret_cast<const void*>(&gemm8<0, 1>),
                            hipFuncAttributeMaxDynamicSharedMemorySize, LDS8);

  // 1) x -> bf16
  cvt_kernel<<<2048, 256, 0, stream>>>(x, xb, 2097152L);

  // 2) W -> W^T bf16 (Wtq,Wtk contiguous => QK merged B-operand)
  dim3 tb(32, 32);
  transposeW_kernel<<<dim3(32, 32), tb, 0, stream>>>(Wq, Wtq);
  transposeW_kernel<<<dim3(32, 32), tb, 0, stream>>>(Wk, Wtk);
  transposeW_kernel<<<dim3(32, 32), tb, 0, stream>>>(Wv, Wtv);

  // 3) merged QK: [8192][2048] = xb @ [Wtq;Wtk]^T + [bq|bk]  (256 wgs)
  gemm8<1, 0><<<dim3(8, 32, 1), 512, LDS8, stream>>>(
      xb, Wtq, bq, bk, QKb, 1024, 1024, 1024, 2048, 0, 0, 0, 1.0f);

  // 4) V^T direct: Vt[e][s] = sum_d Wtv[e][d]*x[s][d] + bv[e]  (128 wgs)
  gemm8<2, 0><<<dim3(32, 4, 1), 512, LDS8, stream>>>(
      Wtv, xb, bv, nullptr, Vt, 1024, 1024, 1024, 8192, 0, 0, 0, 1.0f);

  // 5) scores = Q.K^T/32 (A=QKb Q-cols, B=QKb K-cols; 256 wgs)
  gemm8<0, 0><<<dim3(8, 8, 4), 512, LDS8, stream>>>(
      QKb, QKb + 1024, nullptr, nullptr, SP, 1024, 2048, 2048, 2048,
      2048L * 2048, 2048L * 2048, 2048L * 2048, 0.03125f);

  // 6) softmax over all 8192 rows
  softmax_kernel<<<8192, 256, 0, stream>>>(SP);

  // 7) out = P.V  (B=Vt, ldb=8192, per-batch col offset 2048; 128 wgs)
  gemm8<0, 1><<<dim3(4, 8, 4), 512, LDS8, stream>>>(
      SP, Vt, nullptr, nullptr, out, 2048, 2048, 8192, 1024, 2048L * 2048,
      2048L, 2048L * 1024, 1.0f);
}